// Round 5
// baseline (29979.352 us; speedup 1.0000x reference)
//
#include <hip/hip_runtime.h>
#include <hip/hip_bf16.h>
#include <cstdint>

#define L_SEQ 8192
#define EMB   2048
#define HID   2048
#define N3H   6144

typedef __attribute__((ext_vector_type(8))) short short8;
typedef __attribute__((ext_vector_type(4))) float f32x4;
typedef __attribute__((ext_vector_type(4))) unsigned int uintx4;

__device__ __forceinline__ unsigned short f2bf(float f) {
    union { float f; unsigned int u; } v; v.f = f;
    unsigned int u = v.u;
    unsigned int lsb = (u >> 16) & 1u;
    u += 0x7fffu + lsb;                 // round-to-nearest-even
    return (unsigned short)(u >> 16);
}

__device__ __forceinline__ float bf2f(unsigned int s) {   // low 16 bits = bf16
    union { unsigned int u; float f; } v;
    v.u = (s & 0xffffu) << 16;
    return v.f;
}
__device__ __forceinline__ float u2f(unsigned int u) {
    union { unsigned int u; float f; } v; v.u = u; return v.f;
}

// ---------------------------------------------------------------- fp32 -> bf16
__global__ void cvt_f32_bf16(const float* __restrict__ src,
                             unsigned short* __restrict__ dst, int n) {
    int i = (blockIdx.x * blockDim.x + threadIdx.x) * 4;
    if (i < n) {
        float4 v = *(const float4*)(src + i);
        ushort4 o;
        o.x = f2bf(v.x); o.y = f2bf(v.y); o.z = f2bf(v.z); o.w = f2bf(v.w);
        *(ushort4*)(dst + i) = o;
    }
}

// ---------------------------------------------------------------- GI = X @ W_ih^T + b_ih  (bf16 MFMA, out bf16)
__global__ __launch_bounds__(256) void gemm_gi(const unsigned short* __restrict__ Xb,
                                               const unsigned short* __restrict__ Wb,
                                               const float* __restrict__ bih,
                                               unsigned short* __restrict__ GIb) {
    __shared__ unsigned short As[128][40];
    __shared__ unsigned short Bs[128][40];
    const int tid = threadIdx.x;
    const int wid = tid >> 6, l = tid & 63;
    const int q = l >> 4, r16 = l & 15;
    const int bm = blockIdx.y, bn = blockIdx.x;
    const int wm = (wid >> 1) * 64, wn = (wid & 1) * 64;

    f32x4 acc[4][4] = {};

    const int srow = tid >> 1, sseg = (tid & 1) * 16;
    const unsigned short* xsrc = Xb + (size_t)(bm * 128 + srow) * 2048 + sseg;
    const unsigned short* wsrc = Wb + (size_t)(bn * 128 + srow) * 2048 + sseg;

    for (int k0 = 0; k0 < 2048; k0 += 32) {
        __syncthreads();
        uint4 va0 = *(const uint4*)(xsrc + k0);
        uint4 va1 = *(const uint4*)(xsrc + k0 + 8);
        uint4 vb0 = *(const uint4*)(wsrc + k0);
        uint4 vb1 = *(const uint4*)(wsrc + k0 + 8);
        *(uint4*)&As[srow][sseg]     = va0;
        *(uint4*)&As[srow][sseg + 8] = va1;
        *(uint4*)&Bs[srow][sseg]     = vb0;
        *(uint4*)&Bs[srow][sseg + 8] = vb1;
        __syncthreads();

        short8 af[4], bfr[4];
#pragma unroll
        for (int i = 0; i < 4; i++) af[i]  = *(const short8*)&As[wm + 16 * i + r16][q * 8];
#pragma unroll
        for (int j = 0; j < 4; j++) bfr[j] = *(const short8*)&Bs[wn + 16 * j + r16][q * 8];
#pragma unroll
        for (int i = 0; i < 4; i++)
#pragma unroll
            for (int j = 0; j < 4; j++)
                acc[i][j] = __builtin_amdgcn_mfma_f32_16x16x32_bf16(af[i], bfr[j], acc[i][j], 0, 0, 0);
    }

#pragma unroll
    for (int j = 0; j < 4; j++) {
        int n = bn * 128 + wn + 16 * j + r16;
        float bias = bih[n];
#pragma unroll
        for (int i = 0; i < 4; i++) {
            int mbase = bm * 128 + wm + 16 * i + q * 4;
#pragma unroll
            for (int p = 0; p < 4; p++) {
                GIb[(size_t)(mbase + p) * N3H + n] = f2bf(acc[i][j][p] + bias);
            }
        }
    }
}

// ---------------------------------------------------------------- persistent GRU scan
// 256 blocks x 256 threads (4 waves, 1 wave/SIMD -> VGPR cap 512).
// Wave w owns the h-pair {8b+2w, 8b+2w+1}: 6 Whh rows, fp32 in registers via
// VOLATILE loads (192 VGPR/lane) — volatile cannot be rematerialized/sunk into
// the loop (R3/R4: compiler demoted plain loads -> per-step L2 re-stream,
// VGPR_Count 68/72 proved it).
//
// Sync: fused self-tagged atomic payload. One u64 chunk per h-pair:
//   { h[2c] bf16 | h[2c+1] bf16 << 16 | tag32 << 32 },  tag = step
// 8-B atomic store => no tearing. No separate signal, no drain: publish is one
// one-way store; consumers poll their own 4 chunks (two dwordx4, one vmcnt).
// Parity double-buffer ch[2][1024]; overwrite safety: block passes barrier(t)
// only after observing ALL chunks tagged t => every block published t =>
// every block consumed t-1 => slot holding t-1 is dead. Poison 0xAAAAAAAA
// never matches tags 1..8192 -> no init needed.
__global__ __launch_bounds__(256, 1) void gru_scan(const float* __restrict__ Whh,
                                                   const float* __restrict__ bhh,
                                                   const unsigned short* __restrict__ GIb,
                                                   unsigned long long* ch) {  // [2][1024]
    __shared__ float h_lds[2][2048];
    const int tid = threadIdx.x;
    const int w = tid >> 6, l = tid & 63;
    const int b = blockIdx.x;
    const int h0 = b * 8 + 2 * w;          // lanes 0,1 own hidx = h0 + l

    // 6 weight rows (g,e): row = g*2048 + h0 + e; acc index r = g*2 + e.
    // volatile: forces true register residency (192 VGPRs).
    f32x4 W[48];
#pragma unroll
    for (int g = 0; g < 3; g++)
#pragma unroll
        for (int e = 0; e < 2; e++) {
            const float* wr = Whh + (size_t)(g * HID + h0 + e) * HID + 4 * l;
#pragma unroll
            for (int i = 0; i < 8; i++)
                W[(g * 2 + e) * 8 + i] = *(volatile const f32x4*)(wr + 256 * i);
        }

    // per-lane bias (lanes 0,1 meaningful)
    float bb0 = 0.f, bb1 = 0.f, bb2 = 0.f;
    if (l < 2) {
        bb0 = bhh[h0 + l];
        bb1 = bhh[HID + h0 + l];
        bb2 = bhh[2 * HID + h0 + l];
    }

    // h(0) = 0
    {
        float4 z4 = {0.f, 0.f, 0.f, 0.f};
        *(float4*)&h_lds[0][8 * tid]     = z4;
        *(float4*)&h_lds[0][8 * tid + 4] = z4;
    }

    // GI(0) prefetch (lanes 0,1)
    unsigned short q0 = 0, q1 = 0, q2 = 0;
    if (l < 2) {
        const unsigned short* gq = GIb + h0 + l;
        q0 = gq[0]; q1 = gq[2048]; q2 = gq[4096];
    }

    for (int t = 0; t < L_SEQ; t++) {
        const int p = t & 1;

        // prefetch GI(t+1) — one full step of slack
        unsigned short n0 = 0, n1 = 0, n2 = 0;
        if (l < 2 && t + 1 < L_SEQ) {
            const unsigned short* gq = GIb + (size_t)(t + 1) * N3H + h0 + l;
            n0 = gq[0]; n1 = gq[2048]; n2 = gq[4096];
        }

        if (t > 0) {
            // poll own 4 chunks (h[8tid..8tid+8)): 2 dwordx4, 1 vmcnt per round
            const unsigned long long* cp = ch + (size_t)p * 1024 + 4 * tid;
            const unsigned int tg = (unsigned int)t;
            uintx4 ra, rb;
            do {
                asm volatile("global_load_dwordx4 %0, %2, off sc0 sc1\n\t"
                             "global_load_dwordx4 %1, %3, off sc0 sc1\n\t"
                             "s_waitcnt vmcnt(0)"
                             : "=v"(ra), "=v"(rb)
                             : "v"(cp), "v"(cp + 2) : "memory");
            } while (ra.y != tg || ra.w != tg || rb.y != tg || rb.w != tg);
            // unpack 8 bf16 -> f32, write 32 B to LDS
            float4 ha, hb2;
            ha.x  = u2f(ra.x << 16); ha.y  = u2f(ra.x & 0xffff0000u);
            ha.z  = u2f(ra.z << 16); ha.w  = u2f(ra.z & 0xffff0000u);
            hb2.x = u2f(rb.x << 16); hb2.y = u2f(rb.x & 0xffff0000u);
            hb2.z = u2f(rb.z << 16); hb2.w = u2f(rb.z & 0xffff0000u);
            *(float4*)&h_lds[p][8 * tid]     = ha;
            *(float4*)&h_lds[p][8 * tid + 4] = hb2;
        }
        __syncthreads();                    // the only barrier per step

        float acc0 = 0.f, acc1 = 0.f, acc2 = 0.f, acc3 = 0.f, acc4 = 0.f, acc5 = 0.f;
#pragma unroll
        for (int i = 0; i < 8; i++) {
            f32x4 hv = *(const f32x4*)&h_lds[p][4 * l + 256 * i];
            acc0 = fmaf(W[i].x,      hv.x, acc0); acc0 = fmaf(W[i].y,      hv.y, acc0);
            acc0 = fmaf(W[i].z,      hv.z, acc0); acc0 = fmaf(W[i].w,      hv.w, acc0);
            acc1 = fmaf(W[8 + i].x,  hv.x, acc1); acc1 = fmaf(W[8 + i].y,  hv.y, acc1);
            acc1 = fmaf(W[8 + i].z,  hv.z, acc1); acc1 = fmaf(W[8 + i].w,  hv.w, acc1);
            acc2 = fmaf(W[16 + i].x, hv.x, acc2); acc2 = fmaf(W[16 + i].y, hv.y, acc2);
            acc2 = fmaf(W[16 + i].z, hv.z, acc2); acc2 = fmaf(W[16 + i].w, hv.w, acc2);
            acc3 = fmaf(W[24 + i].x, hv.x, acc3); acc3 = fmaf(W[24 + i].y, hv.y, acc3);
            acc3 = fmaf(W[24 + i].z, hv.z, acc3); acc3 = fmaf(W[24 + i].w, hv.w, acc3);
            acc4 = fmaf(W[32 + i].x, hv.x, acc4); acc4 = fmaf(W[32 + i].y, hv.y, acc4);
            acc4 = fmaf(W[32 + i].z, hv.z, acc4); acc4 = fmaf(W[32 + i].w, hv.w, acc4);
            acc5 = fmaf(W[40 + i].x, hv.x, acc5); acc5 = fmaf(W[40 + i].y, hv.y, acc5);
            acc5 = fmaf(W[40 + i].z, hv.z, acc5); acc5 = fmaf(W[40 + i].w, hv.w, acc5);
        }
        // butterfly: every lane ends with the full sums
        acc0 += __shfl_xor(acc0, 32); acc1 += __shfl_xor(acc1, 32); acc2 += __shfl_xor(acc2, 32);
        acc3 += __shfl_xor(acc3, 32); acc4 += __shfl_xor(acc4, 32); acc5 += __shfl_xor(acc5, 32);
        acc0 += __shfl_xor(acc0, 16); acc1 += __shfl_xor(acc1, 16); acc2 += __shfl_xor(acc2, 16);
        acc3 += __shfl_xor(acc3, 16); acc4 += __shfl_xor(acc4, 16); acc5 += __shfl_xor(acc5, 16);
        acc0 += __shfl_xor(acc0, 8);  acc1 += __shfl_xor(acc1, 8);  acc2 += __shfl_xor(acc2, 8);
        acc3 += __shfl_xor(acc3, 8);  acc4 += __shfl_xor(acc4, 8);  acc5 += __shfl_xor(acc5, 8);
        acc0 += __shfl_xor(acc0, 4);  acc1 += __shfl_xor(acc1, 4);  acc2 += __shfl_xor(acc2, 4);
        acc3 += __shfl_xor(acc3, 4);  acc4 += __shfl_xor(acc4, 4);  acc5 += __shfl_xor(acc5, 4);
        acc0 += __shfl_xor(acc0, 2);  acc1 += __shfl_xor(acc1, 2);  acc2 += __shfl_xor(acc2, 2);
        acc3 += __shfl_xor(acc3, 2);  acc4 += __shfl_xor(acc4, 2);  acc5 += __shfl_xor(acc5, 2);
        acc0 += __shfl_xor(acc0, 1);  acc1 += __shfl_xor(acc1, 1);  acc2 += __shfl_xor(acc2, 1);
        acc3 += __shfl_xor(acc3, 1);  acc4 += __shfl_xor(acc4, 1);  acc5 += __shfl_xor(acc5, 1);

        // gates: lanes 0 and 1 in parallel (uniform code path; others compute garbage)
        float hr = l ? acc1 : acc0;
        float hz = l ? acc3 : acc2;
        float hn = l ? acc5 : acc4;
        float hprev = h_lds[p][h0 + (l & 1)];
        float r  = 1.f / (1.f + __expf(-(bf2f(q0) + hr + bb0)));
        float z  = 1.f / (1.f + __expf(-(bf2f(q1) + hz + bb1)));
        float xn = bf2f(q2) + r * (hn + bb2);
        xn = fminf(fmaxf(xn, -15.f), 15.f);
        float e2 = __expf(2.f * xn);
        float nn = (e2 - 1.f) / (e2 + 1.f);
        float hnew = z * hprev + (1.f - z) * nn;

        // pack pair + tag, single 8-B atomic publish (lane 0)
        float hodd = __shfl(hnew, 1);
        if (l == 0) {
            unsigned long long pk =
                ((unsigned long long)(unsigned int)(t + 1) << 32) |
                (unsigned long long)((unsigned int)f2bf(hnew) |
                                     ((unsigned int)f2bf(hodd) << 16));
            __hip_atomic_store(ch + (size_t)((t + 1) & 1) * 1024 + 4 * b + w, pk,
                               __ATOMIC_RELAXED, __HIP_MEMORY_SCOPE_AGENT);
        }

        q0 = n0; q1 = n1; q2 = n2;
    }
}

// ---------------------------------------------------------------- out = sigmoid(h . fc_w + fc_b)
// final h: tag 8192 -> parity 0 buffer; chunk c holds h[2c], h[2c+1] as bf16
__global__ void fc_out(const unsigned long long* __restrict__ ch,
                       const float* __restrict__ fw,
                       const float* __restrict__ fb, float* __restrict__ out) {
    __shared__ float red[4];
    const int tid = threadIdx.x;
    const int wid = tid >> 6, l = tid & 63;
    float s = 0.f;
#pragma unroll
    for (int i = 0; i < 4; i++) {
        unsigned long long v = ch[4 * tid + i];
        unsigned int pr = (unsigned int)v;
        s += bf2f(pr) * fw[8 * tid + 2 * i];
        s += u2f(pr & 0xffff0000u) * fw[8 * tid + 2 * i + 1];
    }
    s += __shfl_xor(s, 32); s += __shfl_xor(s, 16); s += __shfl_xor(s, 8);
    s += __shfl_xor(s, 4);  s += __shfl_xor(s, 2);  s += __shfl_xor(s, 1);
    if (l == 0) red[wid] = s;
    __syncthreads();
    if (tid == 0) {
        float tot = red[0] + red[1] + red[2] + red[3] + fb[0];
        out[0] = 1.f / (1.f + __expf(-tot));
    }
}

// ---------------------------------------------------------------- launch
extern "C" void kernel_launch(void* const* d_in, const int* in_sizes, int n_in,
                              void* d_out, int out_size, void* d_ws, size_t ws_size,
                              hipStream_t stream) {
    const float* x   = (const float*)d_in[0];
    const float* Wih = (const float*)d_in[1];
    const float* Whh = (const float*)d_in[2];
    const float* bih = (const float*)d_in[3];
    const float* bhh = (const float*)d_in[4];
    const float* fcw = (const float*)d_in[5];
    const float* fcb = (const float*)d_in[6];
    float* out = (float*)d_out;

    char* ws = (char*)d_ws;
    unsigned short* Xb  = (unsigned short*)ws;                         // 33,554,432 B
    unsigned short* Wb  = (unsigned short*)(ws + 33554432);            // 25,165,824 B
    unsigned short* GIb = (unsigned short*)(ws + 58720256);            // 100,663,296 B
    unsigned long long* ch = (unsigned long long*)(ws + 159383552);    // 16,384 B

    cvt_f32_bf16<<<16384, 256, 0, stream>>>(x,   Xb, L_SEQ * EMB);
    cvt_f32_bf16<<<12288, 256, 0, stream>>>(Wih, Wb, N3H * EMB);

    dim3 gg(48, 64);
    gemm_gi<<<gg, 256, 0, stream>>>(Xb, Wb, bih, GIb);

    gru_scan<<<256, 256, 0, stream>>>(Whh, bhh, GIb, ch);

    fc_out<<<1, 256, 0, stream>>>(ch, fcw, fcb, out);
}

// Round 6
// 23462.102 us; speedup vs baseline: 1.2778x; 1.2778x over previous
//
#include <hip/hip_runtime.h>
#include <hip/hip_bf16.h>
#include <cstdint>

#define L_SEQ 8192
#define EMB   2048
#define HID   2048
#define N3H   6144

typedef __attribute__((ext_vector_type(8))) short short8;
typedef __attribute__((ext_vector_type(4))) float f32x4;
typedef __attribute__((ext_vector_type(4))) unsigned int uintx4;

__device__ __forceinline__ unsigned short f2bf(float f) {
    union { float f; unsigned int u; } v; v.f = f;
    unsigned int u = v.u;
    unsigned int lsb = (u >> 16) & 1u;
    u += 0x7fffu + lsb;                 // round-to-nearest-even
    return (unsigned short)(u >> 16);
}

__device__ __forceinline__ float bf2f(unsigned int s) {   // low 16 bits = bf16
    union { unsigned int u; float f; } v;
    v.u = (s & 0xffffu) << 16;
    return v.f;
}

// 16-B uncached (MALL-coherent) load/store: sc0 sc1 bypass L1+L2
__device__ __forceinline__ uintx4 ld16(const uintx4* p) {
    uintx4 r;
    asm volatile("global_load_dwordx4 %0, %1, off sc0 sc1\n\ts_waitcnt vmcnt(0)"
                 : "=v"(r) : "v"(p) : "memory");
    return r;
}
__device__ __forceinline__ void st16(uintx4* p, uintx4 v) {
    asm volatile("global_store_dwordx4 %0, %1, off sc0 sc1"
                 :: "v"(p), "v"(v) : "memory");
}

// ---------------------------------------------------------------- fp32 -> bf16
__global__ void cvt_f32_bf16(const float* __restrict__ src,
                             unsigned short* __restrict__ dst, int n) {
    int i = (blockIdx.x * blockDim.x + threadIdx.x) * 4;
    if (i < n) {
        float4 v = *(const float4*)(src + i);
        ushort4 o;
        o.x = f2bf(v.x); o.y = f2bf(v.y); o.z = f2bf(v.z); o.w = f2bf(v.w);
        *(ushort4*)(dst + i) = o;
    }
}

// ---------------------------------------------------------------- GI = X @ W_ih^T + b_ih  (bf16 MFMA, out bf16)
__global__ __launch_bounds__(256) void gemm_gi(const unsigned short* __restrict__ Xb,
                                               const unsigned short* __restrict__ Wb,
                                               const float* __restrict__ bih,
                                               unsigned short* __restrict__ GIb) {
    __shared__ unsigned short As[128][40];
    __shared__ unsigned short Bs[128][40];
    const int tid = threadIdx.x;
    const int wid = tid >> 6, l = tid & 63;
    const int q = l >> 4, r16 = l & 15;
    const int bm = blockIdx.y, bn = blockIdx.x;
    const int wm = (wid >> 1) * 64, wn = (wid & 1) * 64;

    f32x4 acc[4][4] = {};

    const int srow = tid >> 1, sseg = (tid & 1) * 16;
    const unsigned short* xsrc = Xb + (size_t)(bm * 128 + srow) * 2048 + sseg;
    const unsigned short* wsrc = Wb + (size_t)(bn * 128 + srow) * 2048 + sseg;

    for (int k0 = 0; k0 < 2048; k0 += 32) {
        __syncthreads();
        uint4 va0 = *(const uint4*)(xsrc + k0);
        uint4 va1 = *(const uint4*)(xsrc + k0 + 8);
        uint4 vb0 = *(const uint4*)(wsrc + k0);
        uint4 vb1 = *(const uint4*)(wsrc + k0 + 8);
        *(uint4*)&As[srow][sseg]     = va0;
        *(uint4*)&As[srow][sseg + 8] = va1;
        *(uint4*)&Bs[srow][sseg]     = vb0;
        *(uint4*)&Bs[srow][sseg + 8] = vb1;
        __syncthreads();

        short8 af[4], bfr[4];
#pragma unroll
        for (int i = 0; i < 4; i++) af[i]  = *(const short8*)&As[wm + 16 * i + r16][q * 8];
#pragma unroll
        for (int j = 0; j < 4; j++) bfr[j] = *(const short8*)&Bs[wn + 16 * j + r16][q * 8];
#pragma unroll
        for (int i = 0; i < 4; i++)
#pragma unroll
            for (int j = 0; j < 4; j++)
                acc[i][j] = __builtin_amdgcn_mfma_f32_16x16x32_bf16(af[i], bfr[j], acc[i][j], 0, 0, 0);
    }

#pragma unroll
    for (int j = 0; j < 4; j++) {
        int n = bn * 128 + wn + 16 * j + r16;
        float bias = bih[n];
#pragma unroll
        for (int i = 0; i < 4; i++) {
            int mbase = bm * 128 + wm + 16 * i + q * 4;
#pragma unroll
            for (int p = 0; p < 4; p++) {
                GIb[(size_t)(mbase + p) * N3H + n] = f2bf(acc[i][j][p] + bias);
            }
        }
    }
}

// ---------------------------------------------------------------- persistent GRU scan
// R3 structure (best: 22.8 ms) + true weight residency:
//  * amdgpu_waves_per_eu(2,2): RA target pinned at 2 waves/SIMD -> 256-VGPR
//    budget (launch_bounds min-waves is only a MIN; RA chased occupancy and
//    demoted the weights in R3/R4/R5 -> per-step 50 MB/step MALL re-stream,
//    ~18 TB/s demanded = the real R3/R4 wall).
//  * Whh/bhh NOT __restrict__: in-loop asm "memory" clobbers then make
//    sinking/remat of the preloaded weight loads illegal.
//  * compiler barrier after preload pins the loads above the loop.
__global__ __attribute__((amdgpu_flat_work_group_size(512, 512), amdgpu_waves_per_eu(2, 2)))
void gru_scan(const float* Whh,
              const float* bhh,
              const unsigned short* __restrict__ GIb,
              uintx4* rec,           // [2][512] records {4 bf16 | tag | pad}
              unsigned int* cnt) {   // [2][8] @64B stride, cumulative hints
    __shared__ float h_lds[2][2048];
    __shared__ float hnew_lds[8];
    const int tid = threadIdx.x;
    const int w = tid >> 6, l = tid & 63;
    const int b = blockIdx.x;
    const int hidx = b * 8 + w;

    // weights: 3 rows (r,z,n) for hidx, fp32 in registers (96 VGPR/lane)
    float4 wreg[3][8];
    float bb[3];
#pragma unroll
    for (int g = 0; g < 3; g++) {
        int r = g * HID + hidx;
        bb[g] = bhh[r];
        const float* wr = Whh + (size_t)r * HID + 4 * l;
#pragma unroll
        for (int i = 0; i < 8; i++) wreg[g][i] = *(const float4*)(wr + 256 * i);
    }
    asm volatile("" ::: "memory");   // pin: weight loads cannot sink below this

    {
        float4 z4 = {0.f, 0.f, 0.f, 0.f};
        *(float4*)&h_lds[0][tid * 4] = z4;
    }
    __syncthreads();

    // GI(0) prefetch (wave-uniform address -> one fetch, broadcast)
    unsigned short gr = GIb[hidx];
    unsigned short gz = GIb[2048 + hidx];
    unsigned short gn = GIb[4096 + hidx];

    for (int t = 0; t < L_SEQ; t++) {
        const int p = t & 1;

        // prefetch GI(t+1): consumed at end of step t+1 -> one step of slack
        unsigned short gr2 = 0, gz2 = 0, gn2 = 0;
        if (t + 1 < L_SEQ) {
            const unsigned short* gq = GIb + (size_t)(t + 1) * N3H + hidx;
            gr2 = gq[0]; gz2 = gq[2048]; gn2 = gq[4096];
        }

        if (t > 0) {
            // 1) tiny counter-hint poll (wave0): 8 words on 8 separate lines
            const unsigned int tgt = 32u * (unsigned)((t + (t & 1)) >> 1);
            if (w == 0) {
                while (1) {
                    unsigned int c = tgt;
                    if (l < 8)
                        c = __hip_atomic_load(&cnt[(size_t)p * 128 + l * 16],
                                              __ATOMIC_RELAXED, __HIP_MEMORY_SCOPE_AGENT);
                    if (__all(c >= tgt)) break;
                }
            }
            __syncthreads();

            // 2) bulk payload read ONCE, tag-verified, retry stragglers only
            const uintx4* rp = rec + (size_t)p * 512 + tid;
            uintx4 rv = ld16(rp);
            while (rv.z != (unsigned int)t) rv = ld16(rp);
            float4 hv;
            hv.x = bf2f(rv.x);
            hv.y = bf2f(rv.x >> 16);
            hv.z = bf2f(rv.y);
            hv.w = bf2f(rv.y >> 16);
            *(float4*)&h_lds[p][4 * tid] = hv;   // 16-B stride: conflict-free
        }
        __syncthreads();

        float hprev = h_lds[p][hidx];

        float a0 = 0.f, a1 = 0.f, a2 = 0.f;
#pragma unroll
        for (int i = 0; i < 8; i++) {
            float4 hv = *(const float4*)&h_lds[p][4 * l + 256 * i];
            a0 = fmaf(wreg[0][i].x, hv.x, a0); a0 = fmaf(wreg[0][i].y, hv.y, a0);
            a0 = fmaf(wreg[0][i].z, hv.z, a0); a0 = fmaf(wreg[0][i].w, hv.w, a0);
            a1 = fmaf(wreg[1][i].x, hv.x, a1); a1 = fmaf(wreg[1][i].y, hv.y, a1);
            a1 = fmaf(wreg[1][i].z, hv.z, a1); a1 = fmaf(wreg[1][i].w, hv.w, a1);
            a2 = fmaf(wreg[2][i].x, hv.x, a2); a2 = fmaf(wreg[2][i].y, hv.y, a2);
            a2 = fmaf(wreg[2][i].z, hv.z, a2); a2 = fmaf(wreg[2][i].w, hv.w, a2);
        }
        a0 += __shfl_xor(a0, 32); a1 += __shfl_xor(a1, 32); a2 += __shfl_xor(a2, 32);
        a0 += __shfl_xor(a0, 16); a1 += __shfl_xor(a1, 16); a2 += __shfl_xor(a2, 16);
        a0 += __shfl_xor(a0, 8);  a1 += __shfl_xor(a1, 8);  a2 += __shfl_xor(a2, 8);
        a0 += __shfl_xor(a0, 4);  a1 += __shfl_xor(a1, 4);  a2 += __shfl_xor(a2, 4);
        a0 += __shfl_xor(a0, 2);  a1 += __shfl_xor(a1, 2);  a2 += __shfl_xor(a2, 2);
        a0 += __shfl_xor(a0, 1);  a1 += __shfl_xor(a1, 1);  a2 += __shfl_xor(a2, 1);

        if (l == 0) {
            float r  = 1.f / (1.f + __expf(-(bf2f(gr) + a0 + bb[0])));
            float z  = 1.f / (1.f + __expf(-(bf2f(gz) + a1 + bb[1])));
            float hn = a2 + bb[2];
            float xn = bf2f(gn) + r * hn;
            xn = fminf(fmaxf(xn, -15.f), 15.f);
            float e  = __expf(2.f * xn);
            float nn = (e - 1.f) / (e + 1.f);
            hnew_lds[w] = z * hprev + (1.f - z) * nn;
        }
        __syncthreads();

        // publish: 2 self-tagged records + 1 counter-hint add
        if (tid < 2) {
            const float* hp = hnew_lds + 4 * tid;
            unsigned int w0 = (unsigned int)f2bf(hp[0]) | ((unsigned int)f2bf(hp[1]) << 16);
            unsigned int w1 = (unsigned int)f2bf(hp[2]) | ((unsigned int)f2bf(hp[3]) << 16);
            uintx4 pk;
            pk.x = w0; pk.y = w1; pk.z = (unsigned int)(t + 1); pk.w = 0u;
            st16(rec + (size_t)((t + 1) & 1) * 512 + 2 * b + tid, pk);
        }
        if (tid == 0)
            __hip_atomic_fetch_add(&cnt[(size_t)((t + 1) & 1) * 128 + (b & 7) * 16], 1u,
                                   __ATOMIC_RELAXED, __HIP_MEMORY_SCOPE_AGENT);

        gr = gr2; gz = gz2; gn = gn2;
    }
}

// ---------------------------------------------------------------- out = sigmoid(h . fc_w + fc_b)
// final h (tag 8192, parity 0) in rec[0][0..512): {4 bf16 | tag | pad}
__global__ void fc_out(const uintx4* __restrict__ rec,
                       const float* __restrict__ fw,
                       const float* __restrict__ fb, float* __restrict__ out) {
    __shared__ float red[8];
    const int tid = threadIdx.x;
    const int wid = tid >> 6, l = tid & 63;
    uintx4 rv = *(rec + tid);     // plain load: prior kernel completion = visible
    float4 wv = *(const float4*)&fw[4 * tid];
    float s = bf2f(rv.x) * wv.x + bf2f(rv.x >> 16) * wv.y +
              bf2f(rv.y) * wv.z + bf2f(rv.y >> 16) * wv.w;
    s += __shfl_xor(s, 32); s += __shfl_xor(s, 16); s += __shfl_xor(s, 8);
    s += __shfl_xor(s, 4);  s += __shfl_xor(s, 2);  s += __shfl_xor(s, 1);
    if (l == 0) red[wid] = s;
    __syncthreads();
    if (tid == 0) {
        float tot = 0.f;
#pragma unroll
        for (int i = 0; i < 8; i++) tot += red[i];
        tot += fb[0];
        out[0] = 1.f / (1.f + __expf(-tot));
    }
}

// ---------------------------------------------------------------- launch
extern "C" void kernel_launch(void* const* d_in, const int* in_sizes, int n_in,
                              void* d_out, int out_size, void* d_ws, size_t ws_size,
                              hipStream_t stream) {
    const float* x   = (const float*)d_in[0];
    const float* Wih = (const float*)d_in[1];
    const float* Whh = (const float*)d_in[2];
    const float* bih = (const float*)d_in[3];
    const float* bhh = (const float*)d_in[4];
    const float* fcw = (const float*)d_in[5];
    const float* fcb = (const float*)d_in[6];
    float* out = (float*)d_out;

    char* ws = (char*)d_ws;
    unsigned short* Xb  = (unsigned short*)ws;                         // 33,554,432 B
    unsigned short* Wb  = (unsigned short*)(ws + 33554432);            // 25,165,824 B
    unsigned short* GIb = (unsigned short*)(ws + 58720256);            // 100,663,296 B
    uintx4* rec         = (uintx4*)(ws + 159383552);                   // 16,384 B
    unsigned int* cnt   = (unsigned int*)(ws + 159399936);             // 1,024 B

    hipMemsetAsync(cnt, 0, 1024, stream);   // counters must start at 0

    cvt_f32_bf16<<<16384, 256, 0, stream>>>(x,   Xb, L_SEQ * EMB);
    cvt_f32_bf16<<<12288, 256, 0, stream>>>(Wih, Wb, N3H * EMB);

    dim3 gg(48, 64);
    gemm_gi<<<gg, 256, 0, stream>>>(Xb, Wb, bih, GIb);

    gru_scan<<<256, 512, 0, stream>>>(Whh, bhh, GIb, rec, cnt);

    fc_out<<<1, 512, 0, stream>>>(rec, fcw, fcb, out);
}